// Round 6
// baseline (355.499 us; speedup 1.0000x reference)
//
#include <hip/hip_runtime.h>
#include <stdint.h>

// positional_spiking_attention — MFMA v6: double-buffered 2-phase GEMM core.
// Row layout for all spike matrices: r = bi*4 + t  (bi = b*L + l, t = time).
// MFMA C/D layout row=(lane>>4)*4+reg -> each lane's f32x4 holds all T=4 time
// steps of one (bi,e) column -> LIF recurrence is lane-local in the epilogue.
// Weights split w = hi + lo (two bf16 planes); near-threshold columns
// (|m-0.5| < 1e-3) are compacted and recomputed with the bit-exact serial
// ascending fp32 chain (quad-per-item). MFMA accumulation-order changes are
// covered by the EPS_FLAG bound (worst-case split error ~3.3e-4 < 1e-3).
//
// GEMM core: 128x128 tile, BK=32, two 24KB LDS buffers (48KB total, 3 blk/CU).
// Each step: issue next-step global_load_lds FIRST, compute current, then one
// __syncthreads() (its vmcnt(0) drain is mostly pre-satisfied) — T3-minimum
// 2-phase from the catalog.
//
// Workspace:
//   0    xsb  bf16 first-LIF spikes [bi*4+t][512] (16MB)
//   16M  qs / 32M ks / 48M vs / 64M sA   (same layout)
//   96M  wsp  4 mats x 2 planes x 512x512 bf16 (4MB)
//   100M list u32 flagged-column ids (cap 5M) ; ~119M cnt

#define T_ 4
#define B_ 4
#define L_ 1024
#define D_ 512
#define BI_ (B_*L_)                 // 4096 (b,l) columns
#define M_ROWS (T_*B_*L_)           // 16384
#define STRIDE4 (B_*L_*D_/4)        // 524288 float4/ushort4 per t-slice
#define INV_STD 0.9999950000374997f
#define EPS_FLAG 1e-3f
#define LIST_CAP 5000000u

typedef unsigned int   u32;
typedef unsigned short u16;
typedef __bf16 bf16x8 __attribute__((ext_vector_type(8)));
typedef float  f32x4  __attribute__((ext_vector_type(4)));

static __device__ __forceinline__ float spike_of(float m) {
  return m > 0.5f ? 1.0f : 0.0f;
}
static __device__ __forceinline__ u16 sbits(float s) {
  return s != 0.0f ? (u16)0x3F80 : (u16)0;
}

__device__ __forceinline__ void gll16(const u16* g, void* l) {
  __builtin_amdgcn_global_load_lds(
      (const __attribute__((address_space(1))) u32*)(const void*)g,
      (__attribute__((address_space(3))) u32*)l, 16, 0, 0);
}

// ---------------- weight split: w -> bf16 hi + bf16 lo (+ cnt zero) ----------
__global__ __launch_bounds__(256) void k_wsplit(const float* __restrict__ qw,
    const float* __restrict__ kw, const float* __restrict__ vw,
    const float* __restrict__ lw, u16* __restrict__ wsp, u32* __restrict__ cnt) {
  int idx = blockIdx.x * 256 + threadIdx.x;   // 262144 (4 mats x 65536 float4)
  if (idx == 0) *cnt = 0;
  int mat = idx >> 16;
  int u = idx & 65535;
  const float* W = mat == 0 ? qw : mat == 1 ? kw : mat == 2 ? vw : lw;
  float4 w = ((const float4*)W)[u];
  float wv[4] = {w.x, w.y, w.z, w.w};
  u16 hb[4], lb[4];
#pragma unroll
  for (int c = 0; c < 4; ++c) {
    __bf16 h = (__bf16)wv[c];
    float r = wv[c] - (float)h;
    __bf16 lo = (__bf16)r;
    hb[c] = __builtin_bit_cast(u16, h);
    lb[c] = __builtin_bit_cast(u16, lo);
  }
  u16* base = wsp + (size_t)mat * 524288;          // [mat][plane][e][d]
  ((ushort4*)base)[u]            = make_ushort4(hb[0], hb[1], hb[2], hb[3]);
  ((ushort4*)(base + 262144))[u] = make_ushort4(lb[0], lb[1], lb[2], lb[3]);
}

// ---------------- first LIF: x[t][bi][d] -> xsb[bi*4+t][d] ----------------
__global__ __launch_bounds__(256) void k_lif_first(const float* __restrict__ x,
                                                   u16* __restrict__ xsb) {
  int idx = blockIdx.x * 256 + threadIdx.x;       // bi*128 + d4
  if (idx >= STRIDE4) return;
  const int bi = idx >> 7, d4 = idx & 127;
  const float4* x4 = (const float4*)x;
  ushort4* o4 = (ushort4*)xsb;
  float m[4], s[4];
  float4 v = x4[idx];
  m[0] = v.x; m[1] = v.y; m[2] = v.z; m[3] = v.w;
#pragma unroll
  for (int c = 0; c < 4; ++c) s[c] = spike_of(m[c]);
  o4[(bi * 4 + 0) * 128 + d4] =
      make_ushort4(sbits(s[0]), sbits(s[1]), sbits(s[2]), sbits(s[3]));
#pragma unroll
  for (int t = 1; t < T_; ++t) {
    v = x4[idx + t * STRIDE4];
    float xv[4] = {v.x, v.y, v.z, v.w};
#pragma unroll
    for (int c = 0; c < 4; ++c) {
      m[c] = m[c] * 0.25f * (1.0f - s[c]) + xv[c];
      s[c] = spike_of(m[c]);
    }
    o4[(bi * 4 + t) * 128 + d4] =
        make_ushort4(sbits(s[0]), sbits(s[1]), sbits(s[2]), sbits(s[3]));
  }
}

// ======= GEMM core v6: 128x128 tile, BK=32, double-buffered 2-phase =========
__device__ __forceinline__ void gemm_core(const u16* __restrict__ Ab,
    const u16* __restrict__ Wp, int row0, int col0, int tid,
    unsigned char* sm, f32x4 (&acc)[4][4]) {
  const int lane = tid & 63;
  const int wid = tid >> 6;
  const int wr = wid >> 1, wc = wid & 1;
  const int la = lane & 15, lg = lane >> 4;

  // staging descriptors: A 8KB (2 units), B 2 planes x 8KB (4 units).
  // rows are 64B (32 bf16) = 4 slots of 16B; source pre-swizzled slot^(r&3),
  // LDS dest linear (global_load_lds constraint), reads apply the same XOR.
  const u16* gA[2]; int lA[2];
#pragma unroll
  for (int u = 0; u < 2; ++u) {
    int lin = u * 4096 + tid * 16;                  // 0..8191
    int r = lin >> 6, slot = (lin >> 4) & 3, gs = slot ^ (r & 3);
    gA[u] = Ab + (size_t)(row0 + r) * 512 + gs * 8;
    lA[u] = lin;
  }
  const u16* gB[4]; int lB[4];
#pragma unroll
  for (int u = 0; u < 4; ++u) {
    int lin = u * 4096 + tid * 16;                  // 0..16383
    int plane = lin >> 13, l2 = lin & 8191;
    int r = l2 >> 6, slot = (l2 >> 4) & 3, gs = slot ^ (r & 3);
    gB[u] = Wp + (size_t)plane * 262144 + (size_t)(col0 + r) * 512 + gs * 8;
    lB[u] = 8192 + lin;
  }

  int offA[4], offB[2][4];
#pragma unroll
  for (int mi = 0; mi < 4; ++mi) {
    int r = wr * 64 + mi * 16 + la;
    offA[mi] = r * 64 + ((lg ^ (r & 3)) << 4);
  }
#pragma unroll
  for (int p = 0; p < 2; ++p)
#pragma unroll
    for (int ni = 0; ni < 4; ++ni) {
      int r = wc * 64 + ni * 16 + la;
      offB[p][ni] = 8192 + p * 8192 + r * 64 + ((lg ^ (r & 3)) << 4);
    }

#pragma unroll
  for (int a = 0; a < 4; ++a)
#pragma unroll
    for (int b = 0; b < 4; ++b) acc[a][b] = (f32x4){0.f, 0.f, 0.f, 0.f};

  // prologue: stage k-step 0 into buffer 0
#pragma unroll
  for (int u = 0; u < 2; ++u) gll16(gA[u], sm + lA[u]);
#pragma unroll
  for (int u = 0; u < 4; ++u) gll16(gB[u], sm + lB[u]);
  __syncthreads();

#pragma unroll 2
  for (int t = 0; t < 16; ++t) {
    const int cur = t & 1;
    const int nb = (cur ^ 1) * 24576;
    if (t < 15) {                       // issue NEXT stage before compute
      const int ko = (t + 1) * 32;
#pragma unroll
      for (int u = 0; u < 2; ++u) gll16(gA[u] + ko, sm + nb + lA[u]);
#pragma unroll
      for (int u = 0; u < 4; ++u) gll16(gB[u] + ko, sm + nb + lB[u]);
    }
    const unsigned char* bb = sm + cur * 24576;
    uint4 af[4];
#pragma unroll
    for (int mi = 0; mi < 4; ++mi) af[mi] = *(const uint4*)(bb + offA[mi]);
#pragma unroll
    for (int p = 0; p < 2; ++p)
#pragma unroll
      for (int ni = 0; ni < 4; ++ni) {
        uint4 bf = *(const uint4*)(bb + offB[p][ni]);
#pragma unroll
        for (int mi = 0; mi < 4; ++mi)
          acc[mi][ni] = __builtin_amdgcn_mfma_f32_16x16x32_bf16(
              __builtin_bit_cast(bf16x8, af[mi]),
              __builtin_bit_cast(bf16x8, bf), acc[mi][ni], 0, 0, 0);
      }
    __syncthreads();   // lgkm drain (reads done) + vmcnt drain (next buf ready)
  }
}

// ------ fused QKV: GEMM + BN + LIF epilogue, LDS-staged coalesced stores ----
__global__ __launch_bounds__(256) void k_gemm_qkv(const u16* __restrict__ Ab,
    const u16* __restrict__ wsp,
    const float* __restrict__ qb2, const float* __restrict__ qg,
    const float* __restrict__ qbe,
    const float* __restrict__ kb2, const float* __restrict__ kg,
    const float* __restrict__ kbe,
    const float* __restrict__ vb2, const float* __restrict__ vg,
    const float* __restrict__ vbe,
    u16* __restrict__ qs, u16* __restrict__ ks, u16* __restrict__ vs,
    u32* __restrict__ list, u32* __restrict__ cnt) {
  __shared__ __align__(16) unsigned char sm[49152];
  const int tid = threadIdx.x;
  const int tz = blockIdx.z;
  const u16* Wp = wsp + (size_t)tz * 524288;
  const float* Bb = tz == 0 ? qb2 : tz == 1 ? kb2 : vb2;
  const float* Gg = tz == 0 ? qg  : tz == 1 ? kg  : vg;
  const float* Be = tz == 0 ? qbe : tz == 1 ? kbe : vbe;
  u16* S          = tz == 0 ? qs  : tz == 1 ? ks  : vs;

  int f = blockIdx.y * 4 + blockIdx.x;
  int tI = (f & 7) * 64 + (f >> 3);
  const int row0 = (tI >> 2) * 128;
  const int col0 = (tI & 3) * 128;

  f32x4 acc[4][4];
  gemm_core(Ab, Wp, row0, col0, tid, sm, acc);

  const int lane = tid & 63;
  const int wid = tid >> 6;
  const int wr = wid >> 1, wc = wid & 1;
  const int la = lane & 15, lg = lane >> 4;

  u16* sm16 = (u16*)sm;                 // 128x128 u16 spike tile (32KB)
#pragma unroll
  for (int ni = 0; ni < 4; ++ni) {
    int cl = wc * 64 + ni * 16 + la;    // local col
    int e = col0 + cl;
    float cs = INV_STD * Gg[e];
    float cb = Bb[e], ct = Be[e];
#pragma unroll
    for (int mi = 0; mi < 4; ++mi) {
      int rl = wr * 64 + mi * 16 + lg * 4;   // local row base (bi*4 aligned)
      int bi = (row0 + rl) >> 2;
      float m = 0.f, s = 0.f;
      int fl = 0;
#pragma unroll
      for (int p = 0; p < 4; ++p) {          // p == t
        float pre = (acc[mi][ni][p] + cb) * cs + ct;
        if (p == 0) m = pre;
        else m = m * 0.25f * (1.0f - s) + pre;
        s = spike_of(m);
        if (fabsf(m - 0.5f) < EPS_FLAG) fl = 1;
        sm16[(rl + p) * 128 + cl] = sbits(s);
      }
      if (fl) {
        u32 pos = atomicAdd(cnt, 1u);
        if (pos < LIST_CAP)
          list[pos] = ((u32)tz << 21) | (u32)(bi * 512 + e);
      }
    }
  }
  __syncthreads();
  // coalesced write-out: 8 passes x 16 rows, 16B per lane
#pragma unroll
  for (int ps = 0; ps < 8; ++ps) {
    int rr = ps * 16 + (tid >> 4);
    int c8 = (tid & 15) * 8;
    uint4 vv = *(const uint4*)(sm16 + rr * 128 + c8);
    *(uint4*)(S + (size_t)(row0 + rr) * 512 + col0 + c8) = vv;
  }
}

// -------- last GEMM + BN -> fp32 out [t][bi][d], LDS-staged stores ----------
__global__ __launch_bounds__(256) void k_gemm_out(const u16* __restrict__ Ab,
    const u16* __restrict__ Wp, const float* __restrict__ bias,
    const float* __restrict__ gamma, const float* __restrict__ beta,
    float* __restrict__ Y) {
  __shared__ __align__(16) unsigned char sm[49152];
  const int tid = threadIdx.x;
  int f = blockIdx.y * 4 + blockIdx.x;
  int tI = (f & 7) * 64 + (f >> 3);
  const int row0 = (tI >> 2) * 128;
  const int col0 = (tI & 3) * 128;

  f32x4 acc[4][4];
  gemm_core(Ab, Wp, row0, col0, tid, sm, acc);

  const int lane = tid & 63;
  const int wid = tid >> 6;
  const int wr = wid >> 1, wc = wid & 1;
  const int la = lane & 15, lg = lane >> 4;

  float* sm32 = (float*)sm;             // 64x128 f32 tile per pass (32KB)
#pragma unroll
  for (int h = 0; h < 2; ++h) {
    if (wr == h) {
#pragma unroll
      for (int ni = 0; ni < 4; ++ni) {
        int cl = wc * 64 + ni * 16 + la;
        int e = col0 + cl;
        float cs = INV_STD * gamma[e];
        float cb = bias[e], ct = beta[e];
#pragma unroll
        for (int mi = 0; mi < 4; ++mi) {
          int rb = mi * 16 + lg * 4;         // local row within pass
#pragma unroll
          for (int p = 0; p < 4; ++p)
            sm32[(rb + p) * 128 + cl] = (acc[mi][ni][p] + cb) * cs + ct;
        }
      }
    }
    __syncthreads();
    // write 64 rows coalesced: 4 threads per row, 128B each
    int rl = tid >> 2;                   // 0..63
    int q0 = (tid & 3) * 32;             // float offset
    int gr = row0 + h * 64 + rl;         // global spike-row = bi*4+p
    int bi = gr >> 2, p = gr & 3;
    float* dst = Y + ((size_t)p * BI_ + bi) * 512 + col0 + q0;
    const float* srcl = sm32 + rl * 128 + q0;
#pragma unroll
    for (int u = 0; u < 8; ++u)
      ((uint4*)dst)[u] = ((const uint4*)srcl)[u];
    __syncthreads();
  }
}

// ------- fixup: quad-per-item, exact serial chain per t, shfl-combine -------
__device__ __forceinline__ void consume32_1(const float4 (&wb)[8],
                                            const uint4 (&ab)[4], float& c) {
#pragma unroll
  for (int u = 0; u < 8; ++u) {           // u = group of 4 consecutive j
    float4 w = wb[u];
    uint4 tt = ab[u >> 1];
    u32 a = (u & 1) ? tt.z : tt.x, b = (u & 1) ? tt.w : tt.y;
    c += (a & 0xFFFFu) ? w.x : 0.0f;      // strict ascending-j order
    c += (a >> 16)     ? w.y : 0.0f;
    c += (b & 0xFFFFu) ? w.z : 0.0f;
    c += (b >> 16)     ? w.w : 0.0f;
  }
}

__global__ __launch_bounds__(128) void k_fixup_c(const u16* __restrict__ xsb,
    u16* __restrict__ qs, u16* __restrict__ ks, u16* __restrict__ vs,
    const float* __restrict__ qw, const float* __restrict__ qb2,
    const float* __restrict__ qg, const float* __restrict__ qbe,
    const float* __restrict__ kw, const float* __restrict__ kb2,
    const float* __restrict__ kg, const float* __restrict__ kbe,
    const float* __restrict__ vw, const float* __restrict__ vb2,
    const float* __restrict__ vg, const float* __restrict__ vbe,
    const u32* __restrict__ list, const u32* __restrict__ cnt) {
  u32 n = *cnt;
  if (n > LIST_CAP) n = LIST_CAP;
  u32 tot = n * 4;
  for (u32 ii = blockIdx.x * 128 + threadIdx.x; ii < tot;
       ii += gridDim.x * 128) {
    u32 i = ii >> 2;
    int t = (int)(ii & 3);
    u32 e = list[i];
    int tz = (int)(e >> 21);
    int col = (int)(e & 0x1FFFFFu);
    int bi = col >> 9, d = col & 511;
    const float* W  = tz == 0 ? qw  : tz == 1 ? kw  : vw;
    const float* Bb = tz == 0 ? qb2 : tz == 1 ? kb2 : vb2;
    const float* Gg = tz == 0 ? qg  : tz == 1 ? kg  : vg;
    const float* Be = tz == 0 ? qbe : tz == 1 ? kbe : vbe;
    u16* S          = tz == 0 ? qs  : tz == 1 ? ks  : vs;
    const float4* w4 = (const float4*)(W + (size_t)d * 512);          // 128
    const uint4*  R  = (const uint4*)(xsb + ((size_t)bi * 4 + t) * 512); // 32

    float4 wA[8], wB[8];
    uint4 aA[4], aB[4];
#pragma unroll
    for (int u = 0; u < 8; ++u) wA[u] = w4[u];
#pragma unroll
    for (int u = 0; u < 4; ++u) aA[u] = R[u];
    float c = 0.f;
#pragma unroll
    for (int ch = 0; ch < 16; ++ch) {     // 16 chunks x 32 j
      if ((ch & 1) == 0) {
        if (ch + 1 < 16) {
          int wb0 = (ch + 1) * 8, ab0 = (ch + 1) * 4;
#pragma unroll
          for (int u = 0; u < 8; ++u) wB[u] = w4[wb0 + u];
#pragma unroll
          for (int u = 0; u < 4; ++u) aB[u] = R[ab0 + u];
        }
        consume32_1(wA, aA, c);
      } else {
        if (ch + 1 < 16) {
          int wb0 = (ch + 1) * 8, ab0 = (ch + 1) * 4;
#pragma unroll
          for (int u = 0; u < 8; ++u) wA[u] = w4[wb0 + u];
#pragma unroll
          for (int u = 0; u < 4; ++u) aA[u] = R[ab0 + u];
        }
        consume32_1(wB, aB, c);
      }
    }
    int lane = threadIdx.x & 63;
    int qb = lane & ~3;
    float cq[4];
    cq[0] = __shfl(c, qb + 0, 64);
    cq[1] = __shfl(c, qb + 1, 64);
    cq[2] = __shfl(c, qb + 2, 64);
    cq[3] = __shfl(c, qb + 3, 64);
    float cs = INV_STD * Gg[d];
    float cb = Bb[d], ct = Be[d];
    float m = 0.f, s = 0.f;
    u16 myb = 0;
#pragma unroll
    for (int t2 = 0; t2 < 4; ++t2) {
      float pre = (cq[t2] + cb) * cs + ct;   // identical to GEMM epilogue
      if (t2 == 0) m = pre;
      else m = m * 0.25f * (1.0f - s) + pre;
      s = spike_of(m);
      if (t2 == t) myb = sbits(s);
    }
    S[((size_t)bi * 4 + t) * 512 + d] = myb;
  }
}

// ---------------- banded positional mixing + attn_lif ----------------
__global__ __launch_bounds__(256) void k_attn(const u16* __restrict__ qs,
    const u16* __restrict__ ks, const u16* __restrict__ vs,
    const float* __restrict__ pos_bias, u16* __restrict__ sout) {
  int idx = blockIdx.x * 256 + threadIdx.x;     // bi*128 + d4
  if (idx >= STRIDE4) return;
  const int d4 = idx & 127;
  const int bi = idx >> 7;
  const int i = bi & (L_ - 1);
  const int wmax = i < 7 ? i : 7;

  float pbv[8];
  const float* pbrow = pos_bias + (size_t)i * L_ + i;
  for (int w = 0; w <= wmax; ++w) pbv[w] = pbrow[-w];

  const ushort4* k4 = (const ushort4*)ks;
  const ushort4* v4 = (const ushort4*)vs;
  const ushort4* q4 = (const ushort4*)qs;
  float pre[T_][4];

#pragma unroll
  for (int t = 0; t < T_; ++t) {
    float sum[4] = {0.f, 0.f, 0.f, 0.f};
    for (int w = wmax; w >= 0; --w) {   // ascending j = i-w
      int rj = ((bi - w) * 4 + t) * 128 + d4;
      ushort4 ku = k4[rj];
      ushort4 vu = v4[rj];
      sum[0] += (ku.x && vu.x) ? pbv[w] : 0.0f;
      sum[1] += (ku.y && vu.y) ? pbv[w] : 0.0f;
      sum[2] += (ku.z && vu.z) ? pbv[w] : 0.0f;
      sum[3] += (ku.w && vu.w) ? pbv[w] : 0.0f;
    }
    ushort4 qu = q4[(bi * 4 + t) * 128 + d4];
    pre[t][0] = qu.x ? sum[0] : 0.0f;
    pre[t][1] = qu.y ? sum[1] : 0.0f;
    pre[t][2] = qu.z ? sum[2] : 0.0f;
    pre[t][3] = qu.w ? sum[3] : 0.0f;
  }

  ushort4* s4 = (ushort4*)sout;
  float m[4], s[4];
#pragma unroll
  for (int c = 0; c < 4; ++c) { m[c] = pre[0][c]; s[c] = spike_of(m[c]); }
  s4[(bi * 4 + 0) * 128 + d4] =
      make_ushort4(sbits(s[0]), sbits(s[1]), sbits(s[2]), sbits(s[3]));
#pragma unroll
  for (int t = 1; t < T_; ++t) {
#pragma unroll
    for (int c = 0; c < 4; ++c) {
      m[c] = m[c] * 0.25f * (1.0f - s[c]) + pre[t][c];
      s[c] = spike_of(m[c]);
    }
    s4[(bi * 4 + t) * 128 + d4] =
        make_ushort4(sbits(s[0]), sbits(s[1]), sbits(s[2]), sbits(s[3]));
  }
}

extern "C" void kernel_launch(void* const* d_in, const int* in_sizes, int n_in,
                              void* d_out, int out_size, void* d_ws, size_t ws_size,
                              hipStream_t stream) {
  (void)in_sizes; (void)n_in; (void)out_size; (void)ws_size;
  const float* x        = (const float*)d_in[0];
  const float* pos_bias = (const float*)d_in[1];
  const float* q_w    = (const float*)d_in[2];
  const float* q_b    = (const float*)d_in[3];
  const float* q_g    = (const float*)d_in[4];
  const float* q_beta = (const float*)d_in[5];
  const float* k_w    = (const float*)d_in[6];
  const float* k_b    = (const float*)d_in[7];
  const float* k_g    = (const float*)d_in[8];
  const float* k_beta = (const float*)d_in[9];
  const float* v_w    = (const float*)d_in[10];
  const float* v_b    = (const float*)d_in[11];
  const float* v_g    = (const float*)d_in[12];
  const float* v_beta = (const float*)d_in[13];
  const float* last_w    = (const float*)d_in[14];
  const float* last_b    = (const float*)d_in[15];
  const float* last_g    = (const float*)d_in[16];
  const float* last_beta = (const float*)d_in[17];
  float* out = (float*)d_out;

  char* ws = (char*)d_ws;
  u16*   xsb  = (u16*)(ws + 0);
  u16*   qs   = (u16*)(ws + 16777216);
  u16*   ks   = (u16*)(ws + 33554432);
  u16*   vs   = (u16*)(ws + 50331648);
  u16*   sA   = (u16*)(ws + 67108864);
  u16*   wsp  = (u16*)(ws + 100663296);
  u32*   list = (u32*)(ws + 104857600);    // 20 MB cap
  u32*   cnt  = (u32*)(ws + 124857600);

  k_wsplit<<<1024, 256, 0, stream>>>(q_w, k_w, v_w, last_w, wsp, cnt);
  k_lif_first<<<2048, 256, 0, stream>>>(x, xsb);

  dim3 gq(4, 128, 3);
  k_gemm_qkv<<<gq, 256, 0, stream>>>(xsb, wsp,
      q_b, q_g, q_beta, k_b, k_g, k_beta, v_b, v_g, v_beta,
      qs, ks, vs, list, cnt);

  k_fixup_c<<<2048, 128, 0, stream>>>(xsb, qs, ks, vs,
      q_w, q_b, q_g, q_beta, k_w, k_b, k_g, k_beta, v_w, v_b, v_g, v_beta,
      list, cnt);

  k_attn<<<2048, 256, 0, stream>>>(qs, ks, vs, pos_bias, sA);

  dim3 gg(4, 128);
  k_gemm_out<<<gg, 256, 0, stream>>>(sA, wsp + 3 * 524288,
                                     last_b, last_g, last_beta, out);
}

// Round 7
// 330.373 us; speedup vs baseline: 1.0761x; 1.0761x over previous
//
#include <hip/hip_runtime.h>
#include <stdint.h>

// positional_spiking_attention — v7: int8 MFMA (2-plane quantized weights).
// Spikes in {0,1} stored as u8 (exact). Weight rows w = s1*a1 + s2*a2 with
// a1,a2 in i8, s1 = rowmax/127, s2 = s1/254 -> residual <= s1/508 ~ 2^-16*max.
// i32 MFMA accumulation is EXACT (<= 512*127 < 2^24), so GEMM error is the
// residual only. Near-threshold columns (|m-0.5| < 1e-3) are compacted and
// recomputed with the bit-exact serial ascending fp32 chain (quad-per-item).
// Row layout for spike matrices: r = bi*4 + t; MFMA C/D layout puts all T=4
// time steps of one (bi,e) column in one lane's 4 accum regs -> LIF fused.
//
// GEMM core: 128x128 tile, BK=128 (4 K-steps), single-buffer 2-barrier loop,
// LDS 48KB: A 16KB + B(2 planes) 32KB; 16B slots, XOR (r&7) swizzle with
// pre-swizzled global source (global_load_lds dest stays linear).
//
// Workspace:
//   0    xsb  u8 first-LIF spikes [bi*4+t][512] (8MB)
//   8M   qs / 16M ks / 24M vs / 32M sA  (u8, same layout)
//   40M  Wq   4 mats x 2 planes x 512x512 i8 (2MB)
//   44M  scl  [mat][2][512] f32 scales (16KB)
//   48M  list u32 flagged-column ids (cap 5M) ; 70M cnt

#define T_ 4
#define B_ 4
#define L_ 1024
#define D_ 512
#define BI_ (B_*L_)                 // 4096 (b,l) columns
#define STRIDE4 (B_*L_*D_/4)        // 524288 4-elem groups per t-slice
#define INV_STD 0.9999950000374997f
#define EPS_FLAG 1e-3f
#define LIST_CAP 5000000u

typedef unsigned int   u32;
typedef unsigned char  u8;
typedef int i32x4 __attribute__((ext_vector_type(4)));

static __device__ __forceinline__ float spike_of(float m) {
  return m > 0.5f ? 1.0f : 0.0f;
}

__device__ __forceinline__ void gll16(const void* g, void* l) {
  __builtin_amdgcn_global_load_lds(
      (const __attribute__((address_space(1))) u32*)g,
      (__attribute__((address_space(3))) u32*)l, 16, 0, 0);
}

// ------ weight quantize: one wave per (mat,row e); w = s1*a1 + s2*a2 --------
__global__ __launch_bounds__(256) void k_wsplit(const float* __restrict__ qw,
    const float* __restrict__ kw, const float* __restrict__ vw,
    const float* __restrict__ lw, u8* __restrict__ Wq,
    float* __restrict__ scl, u32* __restrict__ cnt) {
  if (blockIdx.x == 0 && threadIdx.x == 0) *cnt = 0;
  int gid = blockIdx.x * 4 + (threadIdx.x >> 6);   // wave id 0..2047
  int mat = gid >> 9, e = gid & 511;
  int lane = threadIdx.x & 63;
  const float* W = mat == 0 ? qw : mat == 1 ? kw : mat == 2 ? vw : lw;
  const float4* w4 = (const float4*)(W + (size_t)e * 512 + lane * 8);
  float4 wa = w4[0], wb = w4[1];
  float w[8] = {wa.x, wa.y, wa.z, wa.w, wb.x, wb.y, wb.z, wb.w};
  float am = 0.f;
#pragma unroll
  for (int j = 0; j < 8; ++j) am = fmaxf(am, fabsf(w[j]));
#pragma unroll
  for (int off = 1; off < 64; off <<= 1)
    am = fmaxf(am, __shfl_xor(am, off, 64));
  float s1 = am > 0.f ? am * (1.0f / 127.0f) : 1.0f;
  float s2 = s1 * (1.0f / 254.0f);
  float inv1 = 1.0f / s1, inv2 = 1.0f / s2;
  u32 p1lo = 0, p1hi = 0, p2lo = 0, p2hi = 0;
#pragma unroll
  for (int j = 0; j < 8; ++j) {
    float q1 = rintf(w[j] * inv1);
    q1 = fminf(127.f, fmaxf(-127.f, q1));
    float r = w[j] - s1 * q1;
    float q2 = rintf(r * inv2);
    q2 = fminf(127.f, fmaxf(-127.f, q2));
    u32 b1 = (u32)(u8)(signed char)(int)q1;
    u32 b2 = (u32)(u8)(signed char)(int)q2;
    if (j < 4) { p1lo |= b1 << (j * 8); p2lo |= b2 << (j * 8); }
    else       { p1hi |= b1 << ((j - 4) * 8); p2hi |= b2 << ((j - 4) * 8); }
  }
  u8* base = Wq + (size_t)mat * 524288 + (size_t)e * 512 + lane * 8;
  *(uint2*)base             = make_uint2(p1lo, p1hi);
  *(uint2*)(base + 262144)  = make_uint2(p2lo, p2hi);
  if (lane == 0) {
    scl[mat * 1024 + e] = s1;
    scl[mat * 1024 + 512 + e] = s2;
  }
}

// ---------------- first LIF: x[t][bi][d] -> xsb[bi*4+t][d] (u8) -------------
__global__ __launch_bounds__(256) void k_lif_first(const float* __restrict__ x,
                                                   u8* __restrict__ xsb) {
  int idx = blockIdx.x * 256 + threadIdx.x;       // bi*128 + d4
  if (idx >= STRIDE4) return;
  const int bi = idx >> 7, d4 = idx & 127;
  const float4* x4 = (const float4*)x;
  uchar4* o4 = (uchar4*)xsb;
  float m[4], s[4];
  float4 v = x4[idx];
  m[0] = v.x; m[1] = v.y; m[2] = v.z; m[3] = v.w;
#pragma unroll
  for (int c = 0; c < 4; ++c) s[c] = spike_of(m[c]);
  o4[(bi * 4 + 0) * 128 + d4] =
      make_uchar4((u8)s[0], (u8)s[1], (u8)s[2], (u8)s[3]);
#pragma unroll
  for (int t = 1; t < T_; ++t) {
    v = x4[idx + t * STRIDE4];
    float xv[4] = {v.x, v.y, v.z, v.w};
#pragma unroll
    for (int c = 0; c < 4; ++c) {
      m[c] = m[c] * 0.25f * (1.0f - s[c]) + xv[c];
      s[c] = spike_of(m[c]);
    }
    o4[(bi * 4 + t) * 128 + d4] =
        make_uchar4((u8)s[0], (u8)s[1], (u8)s[2], (u8)s[3]);
  }
}

// ======= GEMM core i8: 128x128 tile, BK=128 (4 steps), 2 i32 acc planes =====
__device__ __forceinline__ void gemm_core_i8(const u8* __restrict__ Ab,
    const u8* __restrict__ Wq2, int row0, int col0, int tid,
    unsigned char* sm, i32x4 (&acc0)[4][4], i32x4 (&acc1)[4][4]) {
  const u8* gsrc[12];
  int loff[12];
#pragma unroll
  for (int u = 0; u < 12; ++u) {
    if (u < 4) {                        // A: 16KB, rows of 128B (8 x 16B slots)
      int lin = u * 4096 + tid * 16;
      int r = lin >> 7, slot = (lin >> 4) & 7, gs = slot ^ (r & 7);
      gsrc[u] = Ab + (size_t)(row0 + r) * 512 + gs * 16;
      loff[u] = lin;
    } else {                            // B: 2 planes x 16KB
      int lin = (u - 4) * 4096 + tid * 16;      // 0..32767
      int plane = lin >> 14, l3 = lin & 16383;
      int r = l3 >> 7, slot = (l3 >> 4) & 7, gs = slot ^ (r & 7);
      gsrc[u] = Wq2 + (size_t)plane * 262144 + (size_t)(col0 + r) * 512 + gs * 16;
      loff[u] = 16384 + lin;
    }
  }
  const int lane = tid & 63;
  const int wid = tid >> 6;
  const int wr = wid >> 1, wc = wid & 1;
  const int la = lane & 15, lg = lane >> 4;

  int offA[4][2], offB[2][4][2];
#pragma unroll
  for (int mi = 0; mi < 4; ++mi) {
    int r = wr * 64 + mi * 16 + la;
#pragma unroll
    for (int ks = 0; ks < 2; ++ks)
      offA[mi][ks] = r * 128 + (((ks * 4 + lg) ^ (r & 7)) << 4);
  }
#pragma unroll
  for (int p = 0; p < 2; ++p)
#pragma unroll
    for (int ni = 0; ni < 4; ++ni) {
      int r = wc * 64 + ni * 16 + la;
#pragma unroll
      for (int ks = 0; ks < 2; ++ks)
        offB[p][ni][ks] = 16384 + p * 16384 + r * 128 +
                          (((ks * 4 + lg) ^ (r & 7)) << 4);
    }

#pragma unroll
  for (int a = 0; a < 4; ++a)
#pragma unroll
    for (int b = 0; b < 4; ++b) {
      acc0[a][b] = (i32x4){0, 0, 0, 0};
      acc1[a][b] = (i32x4){0, 0, 0, 0};
    }

  for (int k0 = 0; k0 < 4; ++k0) {
#pragma unroll
    for (int u = 0; u < 12; ++u) gll16(gsrc[u] + (k0 << 7), sm + loff[u]);
    __syncthreads();
    uint4 af[4][2];
#pragma unroll
    for (int mi = 0; mi < 4; ++mi)
#pragma unroll
      for (int ks = 0; ks < 2; ++ks)
        af[mi][ks] = *(const uint4*)(sm + offA[mi][ks]);
    // plane 0
#pragma unroll
    for (int ks = 0; ks < 2; ++ks)
#pragma unroll
      for (int ni = 0; ni < 4; ++ni) {
        uint4 bf = *(const uint4*)(sm + offB[0][ni][ks]);
#pragma unroll
        for (int mi = 0; mi < 4; ++mi)
          acc0[mi][ni] = __builtin_amdgcn_mfma_i32_16x16x64_i8(
              __builtin_bit_cast(i32x4, af[mi][ks]),
              __builtin_bit_cast(i32x4, bf), acc0[mi][ni], 0, 0, 0);
      }
    // plane 1
#pragma unroll
    for (int ks = 0; ks < 2; ++ks)
#pragma unroll
      for (int ni = 0; ni < 4; ++ni) {
        uint4 bf = *(const uint4*)(sm + offB[1][ni][ks]);
#pragma unroll
        for (int mi = 0; mi < 4; ++mi)
          acc1[mi][ni] = __builtin_amdgcn_mfma_i32_16x16x64_i8(
              __builtin_bit_cast(i32x4, af[mi][ks]),
              __builtin_bit_cast(i32x4, bf), acc1[mi][ni], 0, 0, 0);
      }
    __syncthreads();
  }
}

// ------ fused QKV: i8 GEMM + BN + LIF epilogue, coalesced u8 stores ---------
__global__ __launch_bounds__(256) void k_gemm_qkv(const u8* __restrict__ Ab,
    const u8* __restrict__ Wq, const float* __restrict__ scl,
    const float* __restrict__ qb2, const float* __restrict__ qg,
    const float* __restrict__ qbe,
    const float* __restrict__ kb2, const float* __restrict__ kg,
    const float* __restrict__ kbe,
    const float* __restrict__ vb2, const float* __restrict__ vg,
    const float* __restrict__ vbe,
    u8* __restrict__ qs, u8* __restrict__ ks, u8* __restrict__ vs,
    u32* __restrict__ list, u32* __restrict__ cnt) {
  __shared__ __align__(16) unsigned char sm[49152];
  const int tid = threadIdx.x;
  const int tz = blockIdx.z;
  const u8* Wp = Wq + (size_t)tz * 524288;
  const float* Bb = tz == 0 ? qb2 : tz == 1 ? kb2 : vb2;
  const float* Gg = tz == 0 ? qg  : tz == 1 ? kg  : vg;
  const float* Be = tz == 0 ? qbe : tz == 1 ? kbe : vbe;
  u8* S           = tz == 0 ? qs  : tz == 1 ? ks  : vs;

  int f = blockIdx.y * 4 + blockIdx.x;
  int tI = (f & 7) * 64 + (f >> 3);
  const int row0 = (tI >> 2) * 128;
  const int col0 = (tI & 3) * 128;

  i32x4 acc0[4][4], acc1[4][4];
  gemm_core_i8(Ab, Wp, row0, col0, tid, sm, acc0, acc1);

  const int lane = tid & 63;
  const int wid = tid >> 6;
  const int wr = wid >> 1, wc = wid & 1;
  const int la = lane & 15, lg = lane >> 4;

  u8* sm8 = sm;                         // 128x128 u8 spike tile (16KB)
#pragma unroll
  for (int ni = 0; ni < 4; ++ni) {
    int cl = wc * 64 + ni * 16 + la;    // local col
    int e = col0 + cl;
    float s1 = scl[tz * 1024 + e];
    float s2 = scl[tz * 1024 + 512 + e];
    float cs = INV_STD * Gg[e];
    float cb = Bb[e], ct = Be[e];
#pragma unroll
    for (int mi = 0; mi < 4; ++mi) {
      int rl = wr * 64 + mi * 16 + lg * 4;   // local row base (bi*4 aligned)
      int bi = (row0 + rl) >> 2;
      float m = 0.f, s = 0.f;
      int fl = 0;
#pragma unroll
      for (int p = 0; p < 4; ++p) {          // p == t
        float raw = s1 * (float)acc0[mi][ni][p] + s2 * (float)acc1[mi][ni][p];
        float pre = (raw + cb) * cs + ct;
        if (p == 0) m = pre;
        else m = m * 0.25f * (1.0f - s) + pre;
        s = spike_of(m);
        if (fabsf(m - 0.5f) < EPS_FLAG) fl = 1;
        sm8[(rl + p) * 128 + cl] = (u8)s;
      }
      if (fl) {
        u32 pos = atomicAdd(cnt, 1u);
        if (pos < LIST_CAP)
          list[pos] = ((u32)tz << 21) | (u32)(bi * 512 + e);
      }
    }
  }
  __syncthreads();
  // coalesced write-out: 4 passes x 32 rows, 16B per lane
#pragma unroll
  for (int ps = 0; ps < 4; ++ps) {
    int rr = ps * 32 + (tid >> 3);
    int c16 = (tid & 7) * 16;
    uint4 vv = *(const uint4*)(sm8 + rr * 128 + c16);
    *(uint4*)(S + (size_t)(row0 + rr) * 512 + col0 + c16) = vv;
  }
}

// -------- last GEMM + BN -> fp32 out [t][bi][d], LDS-staged stores ----------
__global__ __launch_bounds__(256) void k_gemm_out(const u8* __restrict__ Ab,
    const u8* __restrict__ Wq, const float* __restrict__ scl,
    const float* __restrict__ bias, const float* __restrict__ gamma,
    const float* __restrict__ beta, float* __restrict__ Y) {
  __shared__ __align__(16) unsigned char sm[49152];
  const int tid = threadIdx.x;
  int f = blockIdx.y * 4 + blockIdx.x;
  int tI = (f & 7) * 64 + (f >> 3);
  const int row0 = (tI >> 2) * 128;
  const int col0 = (tI & 3) * 128;

  i32x4 acc0[4][4], acc1[4][4];
  gemm_core_i8(Ab, Wq + 3 * 524288, row0, col0, tid, sm, acc0, acc1);

  const int lane = tid & 63;
  const int wid = tid >> 6;
  const int wr = wid >> 1, wc = wid & 1;
  const int la = lane & 15, lg = lane >> 4;

  float* sm32 = (float*)sm;             // 64x128 f32 tile per pass (32KB)
#pragma unroll
  for (int h = 0; h < 2; ++h) {
    if (wr == h) {
#pragma unroll
      for (int ni = 0; ni < 4; ++ni) {
        int cl = wc * 64 + ni * 16 + la;
        int e = col0 + cl;
        float s1 = scl[3 * 1024 + e];
        float s2 = scl[3 * 1024 + 512 + e];
        float cs = INV_STD * gamma[e];
        float cb = bias[e], ct = beta[e];
#pragma unroll
        for (int mi = 0; mi < 4; ++mi) {
          int rb = mi * 16 + lg * 4;         // local row within pass
#pragma unroll
          for (int p = 0; p < 4; ++p) {
            float raw = s1 * (float)acc0[mi][ni][p] +
                        s2 * (float)acc1[mi][ni][p];
            sm32[(rb + p) * 128 + cl] = (raw + cb) * cs + ct;
          }
        }
      }
    }
    __syncthreads();
    int rl = tid >> 2;                   // 0..63
    int q0 = (tid & 3) * 32;             // float offset
    int gr = row0 + h * 64 + rl;         // global spike-row = bi*4+p
    int bi = gr >> 2, p = gr & 3;
    float* dst = Y + ((size_t)p * BI_ + bi) * 512 + col0 + q0;
    const float* srcl = sm32 + rl * 128 + q0;
#pragma unroll
    for (int u = 0; u < 8; ++u)
      ((uint4*)dst)[u] = ((const uint4*)srcl)[u];
    __syncthreads();
  }
}

// ------- fixup: quad-per-item, exact serial fp32 chain, shfl-combine --------
__device__ __forceinline__ void consume32_u8(const float4 (&wb)[8],
                                             const uint4 (&ab)[2], float& c) {
#pragma unroll
  for (int u = 0; u < 8; ++u) {           // u = group of 4 consecutive j
    float4 w = wb[u];
    uint4 t = ab[u >> 2];
    u32 word = (u & 3) == 0 ? t.x : (u & 3) == 1 ? t.y
             : (u & 3) == 2 ? t.z : t.w;
    c += (word & 0xFFu)       ? w.x : 0.0f;   // strict ascending-j order
    c += (word & 0xFF00u)     ? w.y : 0.0f;
    c += (word & 0xFF0000u)   ? w.z : 0.0f;
    c += (word >> 24)         ? w.w : 0.0f;
  }
}

__global__ __launch_bounds__(128) void k_fixup_c(const u8* __restrict__ xsb,
    u8* __restrict__ qs, u8* __restrict__ ks, u8* __restrict__ vs,
    const float* __restrict__ qw, const float* __restrict__ qb2,
    const float* __restrict__ qg, const float* __restrict__ qbe,
    const float* __restrict__ kw, const float* __restrict__ kb2,
    const float* __restrict__ kg, const float* __restrict__ kbe,
    const float* __restrict__ vw, const float* __restrict__ vb2,
    const float* __restrict__ vg, const float* __restrict__ vbe,
    const u32* __restrict__ list, const u32* __restrict__ cnt) {
  u32 n = *cnt;
  if (n > LIST_CAP) n = LIST_CAP;
  u32 tot = n * 4;
  for (u32 ii = blockIdx.x * 128 + threadIdx.x; ii < tot;
       ii += gridDim.x * 128) {
    u32 i = ii >> 2;
    int t = (int)(ii & 3);
    u32 e = list[i];
    int tz = (int)(e >> 21);
    int col = (int)(e & 0x1FFFFFu);
    int bi = col >> 9, d = col & 511;
    const float* W  = tz == 0 ? qw  : tz == 1 ? kw  : vw;
    const float* Bb = tz == 0 ? qb2 : tz == 1 ? kb2 : vb2;
    const float* Gg = tz == 0 ? qg  : tz == 1 ? kg  : vg;
    const float* Be = tz == 0 ? qbe : tz == 1 ? kbe : vbe;
    u8* S           = tz == 0 ? qs  : tz == 1 ? ks  : vs;
    const float4* w4 = (const float4*)(W + (size_t)d * 512);            // 128
    const uint4*  R  = (const uint4*)(xsb + ((size_t)bi * 4 + t) * 512); // 32

    float4 wA[8], wB[8];
    uint4 aA[2], aB[2];
#pragma unroll
    for (int u = 0; u < 8; ++u) wA[u] = w4[u];
#pragma unroll
    for (int u = 0; u < 2; ++u) aA[u] = R[u];
    float c = 0.f;
#pragma unroll
    for (int ch = 0; ch < 16; ++ch) {     // 16 chunks x 32 j
      if ((ch & 1) == 0) {
        if (ch + 1 < 16) {
          int wb0 = (ch + 1) * 8, ab0 = (ch + 1) * 2;
#pragma unroll
          for (int u = 0; u < 8; ++u) wB[u] = w4[wb0 + u];
#pragma unroll
          for (int u = 0; u < 2; ++u) aB[u] = R[ab0 + u];
        }
        consume32_u8(wA, aA, c);
      } else {
        if (ch + 1 < 16) {
          int wb0 = (ch + 1) * 8, ab0 = (ch + 1) * 2;
#pragma unroll
          for (int u = 0; u < 8; ++u) wA[u] = w4[wb0 + u];
#pragma unroll
          for (int u = 0; u < 2; ++u) aA[u] = R[ab0 + u];
        }
        consume32_u8(wB, aB, c);
      }
    }
    int lane = threadIdx.x & 63;
    int qb = lane & ~3;
    float cq[4];
    cq[0] = __shfl(c, qb + 0, 64);
    cq[1] = __shfl(c, qb + 1, 64);
    cq[2] = __shfl(c, qb + 2, 64);
    cq[3] = __shfl(c, qb + 3, 64);
    float cs = INV_STD * Gg[d];
    float cb = Bb[d], ct = Be[d];
    float m = 0.f, s = 0.f;
    u8 myb = 0;
#pragma unroll
    for (int t2 = 0; t2 < 4; ++t2) {
      float pre = (cq[t2] + cb) * cs + ct;   // identical to GEMM epilogue form
      if (t2 == 0) m = pre;
      else m = m * 0.25f * (1.0f - s) + pre;
      s = spike_of(m);
      if (t2 == t) myb = (u8)s;
    }
    S[((size_t)bi * 4 + t) * 512 + d] = myb;
  }
}

// ---------------- banded positional mixing + attn_lif (u8) ------------------
__global__ __launch_bounds__(256) void k_attn(const u8* __restrict__ qs,
    const u8* __restrict__ ks, const u8* __restrict__ vs,
    const float* __restrict__ pos_bias, u8* __restrict__ sout) {
  int idx = blockIdx.x * 256 + threadIdx.x;     // bi*128 + d4
  if (idx >= STRIDE4) return;
  const int d4 = idx & 127;
  const int bi = idx >> 7;
  const int i = bi & (L_ - 1);
  const int wmax = i < 7 ? i : 7;

  float pbv[8];
  const float* pbrow = pos_bias + (size_t)i * L_ + i;
  for (int w = 0; w <= wmax; ++w) pbv[w] = pbrow[-w];

  const uchar4* k4 = (const uchar4*)ks;
  const uchar4* v4 = (const uchar4*)vs;
  const uchar4* q4 = (const uchar4*)qs;
  float pre[T_][4];

#pragma unroll
  for (int t = 0; t < T_; ++t) {
    float sum[4] = {0.f, 0.f, 0.f, 0.f};
    for (int w = wmax; w >= 0; --w) {   // ascending j = i-w
      int rj = ((bi - w) * 4 + t) * 128 + d4;
      uchar4 ku = k4[rj];
      uchar4 vu = v4[rj];
      sum[0] += (ku.x && vu.x) ? pbv[w] : 0.0f;
      sum[1] += (ku.y && vu.y) ? pbv[w] : 0.0f;
      sum[2] += (ku.z && vu.z) ? pbv[w] : 0.0f;
      sum[3] += (ku.w && vu.w) ? pbv[w] : 0.0f;
    }
    uchar4 qu = q4[(bi * 4 + t) * 128 + d4];
    pre[t][0] = qu.x ? sum[0] : 0.0f;
    pre[t][1] = qu.y ? sum[1] : 0.0f;
    pre[t][2] = qu.z ? sum[2] : 0.0f;
    pre[t][3] = qu.w ? sum[3] : 0.0f;
  }

  uchar4* s4 = (uchar4*)sout;
  float m[4], s[4];
#pragma unroll
  for (int c = 0; c < 4; ++c) { m[c] = pre[0][c]; s[c] = spike_of(m[c]); }
  s4[(bi * 4 + 0) * 128 + d4] =
      make_uchar4((u8)s[0], (u8)s[1], (u8)s[2], (u8)s[3]);
#pragma unroll
  for (int t = 1; t < T_; ++t) {
#pragma unroll
    for (int c = 0; c < 4; ++c) {
      m[c] = m[c] * 0.25f * (1.0f - s[c]) + pre[t][c];
      s[c] = spike_of(m[c]);
    }
    s4[(bi * 4 + t) * 128 + d4] =
        make_uchar4((u8)s[0], (u8)s[1], (u8)s[2], (u8)s[3]);
  }
}

extern "C" void kernel_launch(void* const* d_in, const int* in_sizes, int n_in,
                              void* d_out, int out_size, void* d_ws, size_t ws_size,
                              hipStream_t stream) {
  (void)in_sizes; (void)n_in; (void)out_size; (void)ws_size;
  const float* x        = (const float*)d_in[0];
  const float* pos_bias = (const float*)d_in[1];
  const float* q_w    = (const float*)d_in[2];
  const float* q_b    = (const float*)d_in[3];
  const float* q_g    = (const float*)d_in[4];
  const float* q_beta = (const float*)d_in[5];
  const float* k_w    = (const float*)d_in[6];
  const float* k_b    = (const float*)d_in[7];
  const float* k_g    = (const float*)d_in[8];
  const float* k_beta = (const float*)d_in[9];
  const float* v_w    = (const float*)d_in[10];
  const float* v_b    = (const float*)d_in[11];
  const float* v_g    = (const float*)d_in[12];
  const float* v_beta = (const float*)d_in[13];
  const float* last_w    = (const float*)d_in[14];
  const float* last_b    = (const float*)d_in[15];
  const float* last_g    = (const float*)d_in[16];
  const float* last_beta = (const float*)d_in[17];
  float* out = (float*)d_out;

  char* ws = (char*)d_ws;
  u8*    xsb  = (u8*)(ws + 0);
  u8*    qs   = (u8*)(ws + 8388608);
  u8*    ks   = (u8*)(ws + 16777216);
  u8*    vs   = (u8*)(ws + 25165824);
  u8*    sA   = (u8*)(ws + 33554432);
  u8*    Wq   = (u8*)(ws + 41943040);      // 4 x 524288
  float* scl  = (float*)(ws + 46137344);   // 4 x 1024 f32
  u32*   list = (u32*)(ws + 50331648);     // 20 MB cap
  u32*   cnt  = (u32*)(ws + 73400320);

  k_wsplit<<<512, 256, 0, stream>>>(q_w, k_w, v_w, last_w, Wq, scl, cnt);
  k_lif_first<<<2048, 256, 0, stream>>>(x, xsb);

  dim3 gq(4, 128, 3);
  k_gemm_qkv<<<gq, 256, 0, stream>>>(xsb, Wq, scl,
      q_b, q_g, q_beta, k_b, k_g, k_beta, v_b, v_g, v_beta,
      qs, ks, vs, list, cnt);

  k_fixup_c<<<2048, 128, 0, stream>>>(xsb, qs, ks, vs,
      q_w, q_b, q_g, q_beta, k_w, k_b, k_g, k_beta, v_w, v_b, v_g, v_beta,
      list, cnt);

  k_attn<<<2048, 256, 0, stream>>>(qs, ks, vs, pos_bias, sA);

  dim3 gg(4, 128);
  k_gemm_out<<<gg, 256, 0, stream>>>(sA, Wq, scl,
                                     last_b, last_g, last_beta, out);
}